// Round 6
// baseline (141.559 us; speedup 1.0000x reference)
//
#include <hip/hip_runtime.h>
#include <hip/hip_bf16.h>

// (N,C,K,H,W) = (4,3,21,128,128), SCALE=0.5 -> Ho=Wo=64, P=4096
// loss = -(W/N) * sum_{n,p,q} gate_p * exp(-0.5*d2) * (S_p . S_q)
//      = -(W/N) * 0.5 * sum_{n,p,q} (gate_p+gate_q) * w_pq * G_pq   (w,G symmetric)
// Triangle tiles: total = sum_{i<j} T_ij + 0.5*sum_i T_ii  with T weighted (gp+gq).
// (The 0.5 symmetrization factor is absorbed by enumerating each off-diag tile once.)
// Per 32x32 subtile: 2 S-MFMAs (K=21 pad 32, f16) + 2 F-MFMAs (hi/lo exact split),
// epilogue w = exp2(min(c*(sq_p+sq_q) - 2c*dot5, 0)), acc += (gp+gq)*w*G.
//
// ws: 128B/pixel records [S f16 x32 (21 data+11 zeros) | f_hi x8 | f_lo x8 | sq | gate | 0...]
//     + 2112 block partials + counter.  Deterministic last-block fixed-tree reduction.

typedef _Float16 v8h __attribute__((ext_vector_type(8)));
typedef float v16f __attribute__((ext_vector_type(16)));

#define NIMG 4
#define KCH 21
#define HIN 128
#define WIN 128
#define PPX 4096
#define TPB 32                 // 128-tiles per axis
#define TRI 528                // TPB*(TPB+1)/2
#define NBLK (NIMG * TRI)      // 2112

#define PART_OFF 0x200000
#define CNT_OFF  0x202200

#define CEXP -0.72134752044448170f   // -0.5*log2(e)
#define M2C   1.44269504088896341f   // -2*CEXP

__device__ __forceinline__ float fexp2(float x) {
#if __has_builtin(__builtin_amdgcn_exp2f)
    return __builtin_amdgcn_exp2f(x);
#else
    return __expf(x * 0.69314718055994531f);
#endif
}

// ---- prep: one 128B record per pixel ----
__global__ __launch_bounds__(256) void prep_kernel(
    const float* __restrict__ img, const float* __restrict__ seg,
    const float* __restrict__ roi, const int* __restrict__ lbl,
    char* __restrict__ ws)
{
    int gid = blockIdx.x * 256 + threadIdx.x;     // 16384
    if (gid == 0) *(unsigned*)(ws + CNT_OFF) = 0u;
    int n = gid >> 12, p = gid & (PPX - 1);
    int y = p >> 6, x = p & 63, iy = 2 * y, ix = 2 * x;
    const float inv_rgb = 1.0f / 15.0f, inv_sxy = 1.0f / 50.0f;

    float rv = roi[((size_t)n * HIN + iy) * WIN + ix];
    int   lb = lbl[((size_t)n * HIN + iy) * WIN + ix];

    union { float4 q[8]; float f[32]; _Float16 e[64]; } rec;

    float maxs = 0.0f;
    #pragma unroll
    for (int k = 0; k < KCH; k++) {
        const float* sp = seg + ((((size_t)n * KCH + k) * HIN + iy) * WIN + ix);
        float2 a = *(const float2*)sp;
        float2 c = *(const float2*)(sp + WIN);
        float s = 0.25f * (a.x + a.y + c.x + c.y);
        maxs = fmaxf(maxs, s);
        rec.e[k] = (_Float16)(s * rv);            // S = seg_bilinear * roi
    }
    #pragma unroll
    for (int k = KCH; k < 32; k++) rec.e[k] = (_Float16)0.f;

    float gate = (lb == 255) ? 1.0f : fmaxf(rv - maxs, 0.0f);

    float f[5];
    f[0] = (float)x * inv_sxy;
    f[1] = (float)y * inv_sxy;
    f[2] = img[(((size_t)n * 3 + 0) * HIN + iy) * WIN + ix] * inv_rgb;
    f[3] = img[(((size_t)n * 3 + 1) * HIN + iy) * WIN + ix] * inv_rgb;
    f[4] = img[(((size_t)n * 3 + 2) * HIN + iy) * WIN + ix] * inv_rgb;

    float sq = 0.f;
    #pragma unroll
    for (int i = 0; i < 5; i++) {
        _Float16 hi = (_Float16)f[i];
        _Float16 lo = (_Float16)(f[i] - (float)hi);
        rec.e[32 + i] = hi; rec.e[40 + i] = lo;
        float fe = (float)hi + (float)lo;
        sq = fmaf(fe, fe, sq);
    }
    #pragma unroll
    for (int i = 5; i < 8; i++) { rec.e[32 + i] = (_Float16)0.f; rec.e[40 + i] = (_Float16)0.f; }

    rec.f[24] = CEXP * sq;
    rec.f[25] = gate;
    rec.f[26] = 0.f; rec.f[27] = 0.f;
    rec.f[28] = 0.f; rec.f[29] = 0.f; rec.f[30] = 0.f; rec.f[31] = 0.f;

    float4* dst = (float4*)(ws + (size_t)gid * 128);
    #pragma unroll
    for (int u = 0; u < 8; u++) dst[u] = rec.q[u];
}

// ---- pairs: block = upper-tri 128x128 tile; waves 2x2 over 64x64; 32x32 subtiles ----
// LDS: 256 records, stride 136 (bank offset 34 -> 2-way only, free; 8B-aligned ops)
#define LSTR 136
#define RED_O  34816
#define FLAG_O 34832
#define LDS_BYTES 34848

__global__ __launch_bounds__(256, 4) void pairs_kernel(
    const char* __restrict__ ws, float* __restrict__ part,
    unsigned* __restrict__ cnt, float* __restrict__ out)
{
    __shared__ __align__(16) char smem[LDS_BYTES];
    int b = blockIdx.x;
    int n = b / TRI, r = b - n * TRI;
    int i = 0, rowlen = TPB;
    while (r >= rowlen) { r -= rowlen; rowlen--; i++; }
    int j = i + r;                                 // i <= j
    bool diag = (i == j);

    int t = threadIdx.x;
    int lane = t & 63, half = lane >> 5, lr = lane & 31, wv = t >> 6;
    int wq = wv & 1, wp = wv >> 1;

    const float4* recs = (const float4*)ws;        // 8 float4 per record
    // stage i-side -> LDS rows 0..127, j-side -> rows 128..255 (skip if diag)
    {
        int ibase = (n * PPX + i * 128) * 8;
        #pragma unroll
        for (int k = 0; k < 4; k++) {
            int v = t + k * 256;
            int row = v >> 3, off = v & 7;
            float4 val = recs[ibase + v];
            char* d = smem + row * LSTR + off * 16;
            *(float2*)d = make_float2(val.x, val.y);
            *(float2*)(d + 8) = make_float2(val.z, val.w);
        }
        if (!diag) {
            int jbase = (n * PPX + j * 128) * 8;
            #pragma unroll
            for (int k = 0; k < 4; k++) {
                int v = t + k * 256;
                int row = v >> 3, off = v & 7;
                float4 val = recs[jbase + v];
                char* d = smem + (128 + row) * LSTR + off * 16;
                *(float2*)d = make_float2(val.x, val.y);
                *(float2*)(d + 8) = make_float2(val.z, val.w);
            }
        }
    }
    __syncthreads();

    int jrow0 = diag ? 0 : 128;

    // B fragments (q side = j tile)
    v8h BS[2][2], BFh[2], BFl[2]; float sqq[2], gq[2];
    #pragma unroll
    for (int s = 0; s < 2; s++) {
        int cr = jrow0 + wq * 64 + s * 32 + lr;
        const char* rb = smem + cr * LSTR;
        union { v8h h; float2 f[2]; } u0, u1, uh, ul;
        u0.f[0] = *(const float2*)(rb + half * 16);
        u0.f[1] = *(const float2*)(rb + half * 16 + 8);
        u1.f[0] = *(const float2*)(rb + 32 + half * 16);
        u1.f[1] = *(const float2*)(rb + 32 + half * 16 + 8);
        uh.f[0] = *(const float2*)(rb + 64);  uh.f[1] = *(const float2*)(rb + 72);
        ul.f[0] = *(const float2*)(rb + 80);  ul.f[1] = *(const float2*)(rb + 88);
        BS[s][0] = u0.h; BS[s][1] = u1.h; BFh[s] = uh.h; BFl[s] = ul.h;
        sqq[s] = *(const float*)(rb + 96);
        gq[s]  = *(const float*)(rb + 100);
    }

    float a0c = 0.f, a1c = 0.f, a2c = 0.f, a3c = 0.f;

    #pragma unroll
    for (int sp = 0; sp < 2; sp++) {
        int pr = wp * 64 + sp * 32 + lr;
        const char* rb = smem + pr * LSTR;
        union { v8h h; float2 f[2]; } a0, a1, af;
        a0.f[0] = *(const float2*)(rb + half * 16);
        a0.f[1] = *(const float2*)(rb + half * 16 + 8);
        a1.f[0] = *(const float2*)(rb + 32 + half * 16);
        a1.f[1] = *(const float2*)(rb + 32 + half * 16 + 8);
        af.f[0] = *(const float2*)(rb + 64 + half * 16);    // half0=hi, half1=lo
        af.f[1] = *(const float2*)(rb + 64 + half * 16 + 8);

        float sqp[16], gp[16];
        int pr0 = wp * 64 + sp * 32 + half * 4;
        #pragma unroll
        for (int rr = 0; rr < 16; rr++) {
            int row = pr0 + (rr & 3) + 8 * (rr >> 2);       // C-layout row
            sqp[rr] = *(const float*)(smem + row * LSTR + 96);
            gp[rr]  = *(const float*)(smem + row * LSTR + 100);
        }

        #pragma unroll
        for (int s = 0; s < 2; s++) {
            v16f z = {0.f,0.f,0.f,0.f,0.f,0.f,0.f,0.f,0.f,0.f,0.f,0.f,0.f,0.f,0.f,0.f};
            v16f c2 = __builtin_amdgcn_mfma_f32_32x32x16_f16(af.h, BFh[s], z, 0, 0, 0);
            c2 = __builtin_amdgcn_mfma_f32_32x32x16_f16(af.h, BFl[s], c2, 0, 0, 0);
            v16f c1 = __builtin_amdgcn_mfma_f32_32x32x16_f16(a0.h, BS[s][0], z, 0, 0, 0);
            c1 = __builtin_amdgcn_mfma_f32_32x32x16_f16(a1.h, BS[s][1], c1, 0, 0, 0);
            float sqv = sqq[s], gv = gq[s];
            #pragma unroll
            for (int rr = 0; rr < 16; rr++) {
                float arg = fmaf(M2C, c2[rr], sqp[rr] + sqv);
                arg = fminf(arg, 0.0f);
                float w = fexp2(arg);
                float v = w * c1[rr];
                float gg = gp[rr] + gv;
                if ((rr & 3) == 0)      a0c = fmaf(gg, v, a0c);
                else if ((rr & 3) == 1) a1c = fmaf(gg, v, a1c);
                else if ((rr & 3) == 2) a2c = fmaf(gg, v, a2c);
                else                    a3c = fmaf(gg, v, a3c);
            }
        }
    }

    float acc = (a0c + a1c) + (a2c + a3c);
    #pragma unroll
    for (int off = 32; off > 0; off >>= 1) acc += __shfl_down(acc, off, 64);
    float* wred = (float*)(smem + RED_O);
    int* flag = (int*)(smem + FLAG_O);
    if ((t & 63) == 0) wred[t >> 6] = acc;
    __syncthreads();
    if (t == 0) {
        float partial = (wred[0] + wred[1]) + (wred[2] + wred[3]);
        if (diag) partial *= 0.5f;
        part[b] = partial;
        __threadfence();
        unsigned old = atomicAdd(cnt, 1u);
        *flag = (old == NBLK - 1) ? 1 : 0;
    }
    __syncthreads();

    if (*flag) {
        __threadfence();
        float v = 0.f;
        #pragma unroll
        for (int k = 0; k < 9; k++) {
            int idx = t + k * 256;
            if (idx < NBLK)
                v += __hip_atomic_load(&part[idx], __ATOMIC_RELAXED,
                                       __HIP_MEMORY_SCOPE_AGENT);
        }
        float* red = (float*)smem;
        red[t] = v;
        __syncthreads();
        #pragma unroll
        for (int off = 128; off > 0; off >>= 1) {
            if (t < off) red[t] += red[t + off];
            __syncthreads();
        }
        // off-diag tiles counted once == symmetrization 0.5 already absorbed;
        // diag tiles carry their own 0.5. No extra factor here.
        if (t == 0) out[0] = red[0] * (-1e-7f / (float)NIMG);
    }
}

extern "C" void kernel_launch(void* const* d_in, const int* in_sizes, int n_in,
                              void* d_out, int out_size, void* d_ws, size_t ws_size,
                              hipStream_t stream) {
    const float* images = (const float*)d_in[0];   // [4,3,128,128]
    const float* seg    = (const float*)d_in[1];   // [4,21,128,128]
    const float* rois   = (const float*)d_in[2];   // [4,128,128]
    const int*   lbl    = (const int*)d_in[3];     // [4,1,128,128]
    float* out = (float*)d_out;
    char*  ws  = (char*)d_ws;
    float* part = (float*)(ws + PART_OFF);
    unsigned* cnt = (unsigned*)(ws + CNT_OFF);

    hipLaunchKernelGGL(prep_kernel, dim3((NIMG * PPX) / 256), dim3(256), 0, stream,
                       images, seg, rois, lbl, ws);
    hipLaunchKernelGGL(pairs_kernel, dim3(NBLK), dim3(256), 0, stream,
                       (const char*)ws, part, cnt, out);
}

// Round 7
// 117.718 us; speedup vs baseline: 1.2025x; 1.2025x over previous
//
#include <hip/hip_runtime.h>
#include <hip/hip_bf16.h>

// (N,C,K,H,W) = (4,3,21,128,128), SCALE=0.5 -> Ho=Wo=64, P=4096
// loss = -(W/N) * sum_{n,p,q} gate_p * exp(-0.5*d2) * (S_p . S_q)
//      = -(W/N) * 0.5 * sum_{n,p,q} (gate_p+gate_q) * w_pq * G_pq   (w,G symmetric)
// Triangle tiles: total = sum_{i<j} T_ij + 0.5*sum_i T_ii  with T weighted (gp+gq).
// Per 32x32 subtile: 2 S-MFMAs (K=21 pad 32, f16) + 2 F-MFMAs (hi/lo exact split),
// epilogue w = exp2(min(c*(sq_p+sq_q) - 2c*dot5, 0)), acc += (gp+gq)*w*G.
//
// R7: anti-spill. R6 spilled (VGPR=64 alloc vs ~118 live -> 25.5 MB scratch writes,
// latency-bound at 79 us). Fix: amdgpu_waves_per_eu(1,4) opens the VGPR budget
// (LDS 34.8 KB already caps occupancy at 4 blocks/CU, so <=128 VGPRs is free),
// plus register diet: B-frags re-read from LDS per subtile, sq/gate read in-loop
// as float2 (broadcast per half-wave, conflict-free).
//
// ws: 128B/pixel records [S f16 x32 (21 data+11 zeros) | f_hi x8 | f_lo x8 | sq | gate | 0...]
//     + 2112 block partials + counter.  Deterministic last-block fixed-tree reduction.

typedef _Float16 v8h __attribute__((ext_vector_type(8)));
typedef float v16f __attribute__((ext_vector_type(16)));

#define NIMG 4
#define KCH 21
#define HIN 128
#define WIN 128
#define PPX 4096
#define TPB 32                 // 128-tiles per axis
#define TRI 528                // TPB*(TPB+1)/2
#define NBLK (NIMG * TRI)      // 2112

#define PART_OFF 0x200000
#define CNT_OFF  0x202200

#define CEXP -0.72134752044448170f   // -0.5*log2(e)
#define M2C   1.44269504088896341f   // -2*CEXP

__device__ __forceinline__ float fexp2(float x) {
#if __has_builtin(__builtin_amdgcn_exp2f)
    return __builtin_amdgcn_exp2f(x);
#else
    return __expf(x * 0.69314718055994531f);
#endif
}

// ---- prep: one 128B record per pixel ----
__global__ __launch_bounds__(256) void prep_kernel(
    const float* __restrict__ img, const float* __restrict__ seg,
    const float* __restrict__ roi, const int* __restrict__ lbl,
    char* __restrict__ ws)
{
    int gid = blockIdx.x * 256 + threadIdx.x;     // 16384
    if (gid == 0) *(unsigned*)(ws + CNT_OFF) = 0u;
    int n = gid >> 12, p = gid & (PPX - 1);
    int y = p >> 6, x = p & 63, iy = 2 * y, ix = 2 * x;
    const float inv_rgb = 1.0f / 15.0f, inv_sxy = 1.0f / 50.0f;

    float rv = roi[((size_t)n * HIN + iy) * WIN + ix];
    int   lb = lbl[((size_t)n * HIN + iy) * WIN + ix];

    union { float4 q[8]; float f[32]; _Float16 e[64]; } rec;

    float maxs = 0.0f;
    #pragma unroll
    for (int k = 0; k < KCH; k++) {
        const float* sp = seg + ((((size_t)n * KCH + k) * HIN + iy) * WIN + ix);
        float2 a = *(const float2*)sp;
        float2 c = *(const float2*)(sp + WIN);
        float s = 0.25f * (a.x + a.y + c.x + c.y);
        maxs = fmaxf(maxs, s);
        rec.e[k] = (_Float16)(s * rv);            // S = seg_bilinear * roi
    }
    #pragma unroll
    for (int k = KCH; k < 32; k++) rec.e[k] = (_Float16)0.f;

    float gate = (lb == 255) ? 1.0f : fmaxf(rv - maxs, 0.0f);

    float f[5];
    f[0] = (float)x * inv_sxy;
    f[1] = (float)y * inv_sxy;
    f[2] = img[(((size_t)n * 3 + 0) * HIN + iy) * WIN + ix] * inv_rgb;
    f[3] = img[(((size_t)n * 3 + 1) * HIN + iy) * WIN + ix] * inv_rgb;
    f[4] = img[(((size_t)n * 3 + 2) * HIN + iy) * WIN + ix] * inv_rgb;

    float sq = 0.f;
    #pragma unroll
    for (int i = 0; i < 5; i++) {
        _Float16 hi = (_Float16)f[i];
        _Float16 lo = (_Float16)(f[i] - (float)hi);
        rec.e[32 + i] = hi; rec.e[40 + i] = lo;
        float fe = (float)hi + (float)lo;
        sq = fmaf(fe, fe, sq);
    }
    #pragma unroll
    for (int i = 5; i < 8; i++) { rec.e[32 + i] = (_Float16)0.f; rec.e[40 + i] = (_Float16)0.f; }

    rec.f[24] = CEXP * sq;
    rec.f[25] = gate;
    rec.f[26] = 0.f; rec.f[27] = 0.f;
    rec.f[28] = 0.f; rec.f[29] = 0.f; rec.f[30] = 0.f; rec.f[31] = 0.f;

    float4* dst = (float4*)(ws + (size_t)gid * 128);
    #pragma unroll
    for (int u = 0; u < 8; u++) dst[u] = rec.q[u];
}

// ---- pairs: block = upper-tri 128x128 tile; waves 2x2 over 64x64; 32x32 subtiles ----
// LDS: 256 records, stride 136 (bank offset 34 -> 2-way only, free; 8B-aligned ops)
#define LSTR 136
#define RED_O  34816
#define FLAG_O 34832
#define LDS_BYTES 34848

__global__ __launch_bounds__(256)
__attribute__((amdgpu_waves_per_eu(1, 4)))
void pairs_kernel(
    const char* __restrict__ ws, float* __restrict__ part,
    unsigned* __restrict__ cnt, float* __restrict__ out)
{
    __shared__ __align__(16) char smem[LDS_BYTES];
    int b = blockIdx.x;
    int n = b / TRI, r = b - n * TRI;
    int i = 0, rowlen = TPB;
    while (r >= rowlen) { r -= rowlen; rowlen--; i++; }
    int j = i + r;                                 // i <= j
    bool diag = (i == j);

    int t = threadIdx.x;
    int lane = t & 63, half = lane >> 5, lr = lane & 31, wv = t >> 6;
    int wq = wv & 1, wp = wv >> 1;

    const float4* recs = (const float4*)ws;        // 8 float4 per record
    // stage i-side -> LDS rows 0..127, j-side -> rows 128..255 (skip if diag)
    {
        int ibase = (n * PPX + i * 128) * 8;
        #pragma unroll
        for (int k = 0; k < 4; k++) {
            int v = t + k * 256;
            int row = v >> 3, off = v & 7;
            float4 val = recs[ibase + v];
            char* d = smem + row * LSTR + off * 16;
            *(float2*)d = make_float2(val.x, val.y);
            *(float2*)(d + 8) = make_float2(val.z, val.w);
        }
        if (!diag) {
            int jbase = (n * PPX + j * 128) * 8;
            #pragma unroll
            for (int k = 0; k < 4; k++) {
                int v = t + k * 256;
                int row = v >> 3, off = v & 7;
                float4 val = recs[jbase + v];
                char* d = smem + (128 + row) * LSTR + off * 16;
                *(float2*)d = make_float2(val.x, val.y);
                *(float2*)(d + 8) = make_float2(val.z, val.w);
            }
        }
    }
    __syncthreads();

    int jrow0 = diag ? 0 : 128;
    float acc = 0.0f;

    #pragma unroll
    for (int sp = 0; sp < 2; sp++) {
        int pr = wp * 64 + sp * 32 + lr;
        const char* rb = smem + pr * LSTR;
        union { v8h h; float2 f[2]; } a0, a1, af;
        a0.f[0] = *(const float2*)(rb + half * 16);
        a0.f[1] = *(const float2*)(rb + half * 16 + 8);
        a1.f[0] = *(const float2*)(rb + 32 + half * 16);
        a1.f[1] = *(const float2*)(rb + 32 + half * 16 + 8);
        af.f[0] = *(const float2*)(rb + 64 + half * 16);    // half0=hi, half1=lo
        af.f[1] = *(const float2*)(rb + 64 + half * 16 + 8);

        int pr0 = wp * 64 + sp * 32 + half * 4;

        #pragma unroll
        for (int s = 0; s < 2; s++) {
            // B fragments read fresh from LDS (keeps live-register count low)
            int cr = jrow0 + wq * 64 + s * 32 + lr;
            const char* cb = smem + cr * LSTR;
            union { v8h h; float2 f[2]; } b0, b1, bh, bl;
            b0.f[0] = *(const float2*)(cb + half * 16);
            b0.f[1] = *(const float2*)(cb + half * 16 + 8);
            b1.f[0] = *(const float2*)(cb + 32 + half * 16);
            b1.f[1] = *(const float2*)(cb + 32 + half * 16 + 8);
            bh.f[0] = *(const float2*)(cb + 64);  bh.f[1] = *(const float2*)(cb + 72);
            bl.f[0] = *(const float2*)(cb + 80);  bl.f[1] = *(const float2*)(cb + 88);
            float2 sgq = *(const float2*)(cb + 96);         // (c*sq_q, gate_q)

            v16f z = {0.f,0.f,0.f,0.f,0.f,0.f,0.f,0.f,0.f,0.f,0.f,0.f,0.f,0.f,0.f,0.f};
            v16f c2 = __builtin_amdgcn_mfma_f32_32x32x16_f16(af.h, bh.h, z, 0, 0, 0);
            c2 = __builtin_amdgcn_mfma_f32_32x32x16_f16(af.h, bl.h, c2, 0, 0, 0);
            v16f c1 = __builtin_amdgcn_mfma_f32_32x32x16_f16(a0.h, b0.h, z, 0, 0, 0);
            c1 = __builtin_amdgcn_mfma_f32_32x32x16_f16(a1.h, b1.h, c1, 0, 0, 0);

            #pragma unroll
            for (int rr = 0; rr < 16; rr++) {
                int row = pr0 + (rr & 3) + 8 * (rr >> 2);   // C-layout row
                float2 sgp = *(const float2*)(smem + row * LSTR + 96);  // broadcast
                float arg = fmaf(M2C, c2[rr], sgp.x + sgq.x);
                arg = fminf(arg, 0.0f);
                float w = fexp2(arg);
                acc = fmaf((sgp.y + sgq.y) * w, c1[rr], acc);
            }
        }
    }

    #pragma unroll
    for (int off = 32; off > 0; off >>= 1) acc += __shfl_down(acc, off, 64);
    float* wred = (float*)(smem + RED_O);
    int* flag = (int*)(smem + FLAG_O);
    if ((t & 63) == 0) wred[t >> 6] = acc;
    __syncthreads();
    if (t == 0) {
        float partial = (wred[0] + wred[1]) + (wred[2] + wred[3]);
        if (diag) partial *= 0.5f;
        part[b] = partial;
        __threadfence();
        unsigned old = atomicAdd(cnt, 1u);
        *flag = (old == NBLK - 1) ? 1 : 0;
    }
    __syncthreads();

    if (*flag) {
        __threadfence();
        float v = 0.f;
        #pragma unroll
        for (int k = 0; k < 9; k++) {
            int idx = t + k * 256;
            if (idx < NBLK)
                v += __hip_atomic_load(&part[idx], __ATOMIC_RELAXED,
                                       __HIP_MEMORY_SCOPE_AGENT);
        }
        float* red = (float*)smem;
        red[t] = v;
        __syncthreads();
        #pragma unroll
        for (int off = 128; off > 0; off >>= 1) {
            if (t < off) red[t] += red[t + off];
            __syncthreads();
        }
        // off-diag tiles counted once == symmetrization 0.5 already absorbed;
        // diag tiles carry their own 0.5. No extra factor here.
        if (t == 0) out[0] = red[0] * (-1e-7f / (float)NIMG);
    }
}

extern "C" void kernel_launch(void* const* d_in, const int* in_sizes, int n_in,
                              void* d_out, int out_size, void* d_ws, size_t ws_size,
                              hipStream_t stream) {
    const float* images = (const float*)d_in[0];   // [4,3,128,128]
    const float* seg    = (const float*)d_in[1];   // [4,21,128,128]
    const float* rois   = (const float*)d_in[2];   // [4,128,128]
    const int*   lbl    = (const int*)d_in[3];     // [4,1,128,128]
    float* out = (float*)d_out;
    char*  ws  = (char*)d_ws;
    float* part = (float*)(ws + PART_OFF);
    unsigned* cnt = (unsigned*)(ws + CNT_OFF);

    hipLaunchKernelGGL(prep_kernel, dim3((NIMG * PPX) / 256), dim3(256), 0, stream,
                       images, seg, rois, lbl, ws);
    hipLaunchKernelGGL(pairs_kernel, dim3(NBLK), dim3(256), 0, stream,
                       (const char*)ws, part, cnt, out);
}

// Round 8
// 85.182 us; speedup vs baseline: 1.6618x; 1.3820x over previous
//
#include <hip/hip_runtime.h>
#include <hip/hip_bf16.h>

// (N,C,K,H,W) = (4,3,21,128,128), SCALE=0.5 -> Ho=Wo=64, P=4096
// loss = -(W/N) * sum_{n,p,q} gate_p * exp(-0.5*d2) * (S_p . S_q)
// Triangle tiles; per 128x128 tile all weighting is folded into two MFMA chains:
//   c1 = gS_p·S_q + S_p·gS_q = (gp+gq)(S_p·S_q)      [K=48: A=[gS|S], B=[S|gS], 3 MFMAs]
//   c2 = f_p·f_q - 0.5sq_p - 0.5sq_q = -0.5*d2 EXACT [2 MFMAs, f16 hi/lo + sq hi/lo]
//     featA = [hi(5),sqh,sql,1 | lo(5),0,0,1]
//     featB1= [hi(5),1,1,sqh   | hi(5),0,0,sql]
//     featB2= [lo(5),0,0,0     | lo(5),0,0,0]
//   w = exp2(min(log2e * c2, 0));  acc += w * c1     (epilogue: 3 VALU + exp, NO LDS)
// total = sum_{i<j} T_ij + 0.5 sum_i T_ii ; out = -1e-7/N * total.
//
// ws: WS_S 96B/pixel [gS(24 f16)|S(24 f16)], WS_F 96B/pixel [featA|featB1|featB2],
//     PART 2112 f32. Separate deterministic finalize kernel.

typedef _Float16 v8h __attribute__((ext_vector_type(8)));
typedef float v16f __attribute__((ext_vector_type(16)));

#define NIMG 4
#define KCH 21
#define HIN 128
#define WIN 128
#define PPX 4096
#define TPB 32                 // 128-tiles per axis
#define TRI 528                // TPB*(TPB+1)/2
#define NBLK (NIMG * TRI)      // 2112

#define WS_S_OFF 0x000000
#define WS_F_OFF 0x180000
#define PART_OFF 0x300000

#define LOG2E 1.44269504088896341f

__device__ __forceinline__ float fexp2(float x) {
#if __has_builtin(__builtin_amdgcn_exp2f)
    return __builtin_amdgcn_exp2f(x);
#else
    return __expf(x * 0.69314718055994531f);
#endif
}

// ---- prep: per pixel, one 96B S-record and one 96B F-record ----
__global__ __launch_bounds__(256) void prep_kernel(
    const float* __restrict__ img, const float* __restrict__ seg,
    const float* __restrict__ roi, const int* __restrict__ lbl,
    char* __restrict__ ws)
{
    int gid = blockIdx.x * 256 + threadIdx.x;     // 16384
    int n = gid >> 12, p = gid & (PPX - 1);
    int y = p >> 6, x = p & 63, iy = 2 * y, ix = 2 * x;
    const float inv_rgb = 1.0f / 15.0f, inv_sxy = 1.0f / 50.0f;

    float rv = roi[((size_t)n * HIN + iy) * WIN + ix];
    int   lb = lbl[((size_t)n * HIN + iy) * WIN + ix];

    float sv[KCH]; float maxs = 0.0f;
    #pragma unroll
    for (int k = 0; k < KCH; k++) {
        const float* sp = seg + ((((size_t)n * KCH + k) * HIN + iy) * WIN + ix);
        float2 a = *(const float2*)sp;
        float2 c = *(const float2*)(sp + WIN);
        float s = 0.25f * (a.x + a.y + c.x + c.y);
        maxs = fmaxf(maxs, s);
        sv[k] = s * rv;
    }
    float gate = (lb == 255) ? 1.0f : fmaxf(rv - maxs, 0.0f);

    union { float4 q[6]; _Float16 e[48]; } rs;
    #pragma unroll
    for (int k = 0; k < KCH; k++) {
        _Float16 s = (_Float16)sv[k];
        rs.e[k] = (_Float16)(sv[k] * gate);       // gS
        rs.e[24 + k] = s;                         // S
    }
    #pragma unroll
    for (int k = KCH; k < 24; k++) { rs.e[k] = (_Float16)0.f; rs.e[24 + k] = (_Float16)0.f; }

    float f[5];
    f[0] = (float)x * inv_sxy;
    f[1] = (float)y * inv_sxy;
    f[2] = img[(((size_t)n * 3 + 0) * HIN + iy) * WIN + ix] * inv_rgb;
    f[3] = img[(((size_t)n * 3 + 1) * HIN + iy) * WIN + ix] * inv_rgb;
    f[4] = img[(((size_t)n * 3 + 2) * HIN + iy) * WIN + ix] * inv_rgb;

    _Float16 hi[5], lo[5];
    float sq = 0.f;
    #pragma unroll
    for (int u = 0; u < 5; u++) {
        hi[u] = (_Float16)f[u];
        lo[u] = (_Float16)(f[u] - (float)hi[u]);
        float fe = (float)hi[u] + (float)lo[u];
        sq = fmaf(fe, fe, sq);
    }
    float sqv = -0.5f * sq;
    _Float16 sqh = (_Float16)sqv;
    _Float16 sql = (_Float16)(sqv - (float)sqh);
    const _Float16 h0 = (_Float16)0.f, h1 = (_Float16)1.f;

    union { float4 q[6]; _Float16 e[48]; } rf;
    #pragma unroll
    for (int u = 0; u < 5; u++) {
        rf.e[u] = hi[u];       rf.e[8 + u] = lo[u];        // featA
        rf.e[16 + u] = hi[u];  rf.e[24 + u] = hi[u];       // featB1
        rf.e[32 + u] = lo[u];  rf.e[40 + u] = lo[u];       // featB2
    }
    rf.e[5] = sqh; rf.e[6] = sql; rf.e[7] = h1;            // featA k5..7
    rf.e[13] = h0; rf.e[14] = h0; rf.e[15] = h1;           // featA k13..15
    rf.e[21] = h1; rf.e[22] = h1; rf.e[23] = sqh;          // featB1 k5..7
    rf.e[29] = h0; rf.e[30] = h0; rf.e[31] = sql;          // featB1 k13..15
    rf.e[37] = h0; rf.e[38] = h0; rf.e[39] = h0;           // featB2 k5..7
    rf.e[45] = h0; rf.e[46] = h0; rf.e[47] = h0;           // featB2 k13..15

    float4* ds = (float4*)(ws + WS_S_OFF + (size_t)gid * 96);
    float4* df = (float4*)(ws + WS_F_OFF + (size_t)gid * 96);
    #pragma unroll
    for (int u = 0; u < 6; u++) { ds[u] = rs.q[u]; df[u] = rf.q[u]; }
}

// ---- pairs: block = upper-tri 128x128 tile; waves 2x2 over 64x64; 32x32 subtiles ----
// LDS: S-region 256 rows x 104B (96 data; 26 dw stride, gcd 2 -> 2-way, free)
//      F-region 256 rows x 104B
#define LSTR 104
#define SREG_O 0
#define FREG_O 26624
#define RED_O  53248
#define LDS_BYTES 53280

__global__ __launch_bounds__(256)
__attribute__((amdgpu_waves_per_eu(1, 4)))
void pairs_kernel(
    const char* __restrict__ ws, float* __restrict__ part)
{
    __shared__ __align__(16) char smem[LDS_BYTES];
    int b = blockIdx.x;
    int n = b / TRI, r = b - n * TRI;
    int i = 0, rowlen = TPB;
    while (r >= rowlen) { r -= rowlen; rowlen--; i++; }
    int j = i + r;                                 // i <= j
    bool diag = (i == j);

    int t = threadIdx.x;
    int lane = t & 63, half = lane >> 5, lr = lane & 31, wv = t >> 6;
    int wq = wv & 1, wp = wv >> 1;

    // ---- stage: i-tile -> rows 0..127, j-tile -> rows 128..255 ----
    {
        const float4* gsi = (const float4*)(ws + WS_S_OFF) + (size_t)(n * PPX + i * 128) * 6;
        const float4* gfi = (const float4*)(ws + WS_F_OFF) + (size_t)(n * PPX + i * 128) * 6;
        #pragma unroll
        for (int k = 0; k < 3; k++) {
            int v = t + k * 256;                   // 0..767
            int row = v / 6, off = v - row * 6;
            float4 vs = gsi[v], vf = gfi[v];
            char* dS = smem + SREG_O + row * LSTR + off * 16;
            char* dF = smem + FREG_O + row * LSTR + off * 16;
            *(float2*)dS = make_float2(vs.x, vs.y);
            *(float2*)(dS + 8) = make_float2(vs.z, vs.w);
            *(float2*)dF = make_float2(vf.x, vf.y);
            *(float2*)(dF + 8) = make_float2(vf.z, vf.w);
        }
        if (!diag) {
            const float4* gsj = (const float4*)(ws + WS_S_OFF) + (size_t)(n * PPX + j * 128) * 6;
            const float4* gfj = (const float4*)(ws + WS_F_OFF) + (size_t)(n * PPX + j * 128) * 6;
            #pragma unroll
            for (int k = 0; k < 3; k++) {
                int v = t + k * 256;
                int row = v / 6, off = v - row * 6;
                float4 vs = gsj[v], vf = gfj[v];
                char* dS = smem + SREG_O + (128 + row) * LSTR + off * 16;
                char* dF = smem + FREG_O + (128 + row) * LSTR + off * 16;
                *(float2*)dS = make_float2(vs.x, vs.y);
                *(float2*)(dS + 8) = make_float2(vs.z, vs.w);
                *(float2*)dF = make_float2(vf.x, vf.y);
                *(float2*)(dF + 8) = make_float2(vf.z, vf.w);
            }
        }
    }
    __syncthreads();

    int jrow0 = diag ? 0 : 128;
    float acc = 0.0f;

    #pragma unroll
    for (int sp = 0; sp < 2; sp++) {
        // A-side fragments (p-row = wp*64 + sp*32 + lr), k = half*8 within each slice
        int pr = wp * 64 + sp * 32 + lr;
        const char* sb = smem + SREG_O + pr * LSTR;
        const char* fb = smem + FREG_O + pr * LSTR;
        union { v8h h; float2 f[2]; } A0, A1, A2, Af;
        A0.f[0] = *(const float2*)(sb + half * 16);         // gS[0:16]
        A0.f[1] = *(const float2*)(sb + half * 16 + 8);
        A1.f[0] = *(const float2*)(sb + 32 + half * 16);    // gS[16:24]|S[0:8]
        A1.f[1] = *(const float2*)(sb + 32 + half * 16 + 8);
        A2.f[0] = *(const float2*)(sb + 64 + half * 16);    // S[8:24]
        A2.f[1] = *(const float2*)(sb + 64 + half * 16 + 8);
        Af.f[0] = *(const float2*)(fb + half * 16);         // featA
        Af.f[1] = *(const float2*)(fb + half * 16 + 8);

        #pragma unroll
        for (int s = 0; s < 2; s++) {
            // B-side fragments (q-col = jrow0 + wq*64 + s*32 + lr)
            int cr = jrow0 + wq * 64 + s * 32 + lr;
            const char* cb = smem + SREG_O + cr * LSTR;
            const char* gb = smem + FREG_O + cr * LSTR;
            union { v8h h; float2 f[2]; } B0, B1, B2, Bf1, Bf2;
            B0.f[0] = *(const float2*)(cb + 48 + half * 16);        // S[0:16]
            B0.f[1] = *(const float2*)(cb + 48 + half * 16 + 8);
            int o1 = half ? 0 : 80;                                 // S[16:24]|gS[0:8]
            B1.f[0] = *(const float2*)(cb + o1);
            B1.f[1] = *(const float2*)(cb + o1 + 8);
            B2.f[0] = *(const float2*)(cb + 16 + half * 16);        // gS[8:24]
            B2.f[1] = *(const float2*)(cb + 16 + half * 16 + 8);
            Bf1.f[0] = *(const float2*)(gb + 32 + half * 16);       // featB1
            Bf1.f[1] = *(const float2*)(gb + 32 + half * 16 + 8);
            Bf2.f[0] = *(const float2*)(gb + 64 + half * 16);       // featB2
            Bf2.f[1] = *(const float2*)(gb + 64 + half * 16 + 8);

            v16f z = {0.f,0.f,0.f,0.f,0.f,0.f,0.f,0.f,0.f,0.f,0.f,0.f,0.f,0.f,0.f,0.f};
            v16f c2 = __builtin_amdgcn_mfma_f32_32x32x16_f16(Af.h, Bf1.h, z, 0, 0, 0);
            c2 = __builtin_amdgcn_mfma_f32_32x32x16_f16(Af.h, Bf2.h, c2, 0, 0, 0);
            v16f c1 = __builtin_amdgcn_mfma_f32_32x32x16_f16(A0.h, B0.h, z, 0, 0, 0);
            c1 = __builtin_amdgcn_mfma_f32_32x32x16_f16(A1.h, B1.h, c1, 0, 0, 0);
            c1 = __builtin_amdgcn_mfma_f32_32x32x16_f16(A2.h, B2.h, c1, 0, 0, 0);

            #pragma unroll
            for (int rr = 0; rr < 16; rr++) {
                float arg = fminf(LOG2E * c2[rr], 0.0f);   // c2 = -0.5*d2 (exact)
                acc = fmaf(fexp2(arg), c1[rr], acc);       // c1 = (gp+gq)*G
            }
        }
    }

    #pragma unroll
    for (int off = 32; off > 0; off >>= 1) acc += __shfl_down(acc, off, 64);
    float* wred = (float*)(smem + RED_O);
    if ((t & 63) == 0) wred[t >> 6] = acc;
    __syncthreads();
    if (t == 0) {
        float partial = (wred[0] + wred[1]) + (wred[2] + wred[3]);
        if (diag) partial *= 0.5f;                 // diag tiles double-count (p,q)/(q,p)
        part[b] = partial;
    }
}

// ---- finalize: deterministic fixed-tree sum of 2112 partials ----
__global__ __launch_bounds__(256) void finalize_kernel(
    const float* __restrict__ part, float* __restrict__ out)
{
    __shared__ float s[256];
    int t = threadIdx.x;
    float v = 0.f;
    #pragma unroll
    for (int k = 0; k < 9; k++) {
        int idx = t + k * 256;
        if (idx < NBLK) v += part[idx];
    }
    s[t] = v;
    __syncthreads();
    #pragma unroll
    for (int off = 128; off > 0; off >>= 1) {
        if (t < off) s[t] += s[t + off];
        __syncthreads();
    }
    if (t == 0) out[0] = s[0] * (-1e-7f / (float)NIMG);
}

extern "C" void kernel_launch(void* const* d_in, const int* in_sizes, int n_in,
                              void* d_out, int out_size, void* d_ws, size_t ws_size,
                              hipStream_t stream) {
    const float* images = (const float*)d_in[0];   // [4,3,128,128]
    const float* seg    = (const float*)d_in[1];   // [4,21,128,128]
    const float* rois   = (const float*)d_in[2];   // [4,128,128]
    const int*   lbl    = (const int*)d_in[3];     // [4,1,128,128]
    float* out = (float*)d_out;
    char*  ws  = (char*)d_ws;
    float* part = (float*)(ws + PART_OFF);

    hipLaunchKernelGGL(prep_kernel, dim3((NIMG * PPX) / 256), dim3(256), 0, stream,
                       images, seg, rois, lbl, ws);
    hipLaunchKernelGGL(pairs_kernel, dim3(NBLK), dim3(256), 0, stream,
                       (const char*)ws, part);
    hipLaunchKernelGGL(finalize_kernel, dim3(1), dim3(256), 0, stream,
                       (const float*)part, out);
}